// Round 1
// baseline (1422.407 us; speedup 1.0000x reference)
//
#include <hip/hip_runtime.h>
#include <math.h>

// Problem constants
#define BSZ 8
#define CW  32      // WIDTH (channels)
#define NN  256     // NX = NY
#define MM  16      // modes M1 = M2
#define NL  4
#define HID 128

static __device__ __forceinline__ float gelu_f(float v) {
    return 0.5f * v * (1.0f + erff(v * 0.70710678118654752f));
}

#define TWO_PI_OVER_N (6.28318530717958647692f / 256.0f)

// ---------------------------------------------------------------------------
// Lifting: inp = [bc0,bc1,bc2,x,y] @ mlp1_w + mlp1_b  -> h (B, C, NX, NY)
// grid 2048, block 256  (thread per (b,x,y) point)
// ---------------------------------------------------------------------------
__global__ void k_lift(const float* __restrict__ bc, const float* __restrict__ xg,
                       const float* __restrict__ yg, const float* __restrict__ w,
                       const float* __restrict__ bias, float* __restrict__ h) {
    int idx = blockIdx.x * 256 + threadIdx.x;   // over B*N*N
    int b = idx >> 16, pos = idx & 65535;
    float i0 = bc[b * 3 + 0], i1 = bc[b * 3 + 1], i2 = bc[b * 3 + 2];
    float i3 = xg[idx], i4 = yg[idx];
#pragma unroll
    for (int c = 0; c < CW; ++c) {
        float v = i0 * w[c] + i1 * w[CW + c] + i2 * w[2 * CW + c]
                + i3 * w[3 * CW + c] + i4 * w[4 * CW + c] + bias[c];
        h[((size_t)(b * CW + c) << 16) + pos] = v;
    }
}

// ---------------------------------------------------------------------------
// Forward DFT along y: Gy[row, ky] = sum_y h[row,y] * e^{-i 2pi ky y / 256}
// rows = B*C*NX = 65536.  8 rows per block.  grid 8192, block 256.
// thread t: row r=t>>5, ky=(t>>1)&15, part=t&1 (0=re, 1=im)
// gy layout: (row, ky, part)
// ---------------------------------------------------------------------------
__global__ void k_fwd_y(const float* __restrict__ h, float* __restrict__ gy) {
    __shared__ float tile[8 * 256];
    __shared__ float ct[256], st[256];
    int tid = threadIdx.x;
    {
        float ang = (float)tid * TWO_PI_OVER_N;
        ct[tid] = cosf(ang);
        st[tid] = sinf(ang);
    }
    size_t base = (size_t)blockIdx.x * 2048;
#pragma unroll
    for (int i = 0; i < 8; ++i) tile[i * 256 + tid] = h[base + i * 256 + tid];
    __syncthreads();

    int r = tid >> 5, ky = (tid >> 1) & 15, part = tid & 1;
    const float* tw = part ? st : ct;
    const float* row = &tile[r * 256];
    float acc = 0.f;
    int idx = 0;
#pragma unroll 8
    for (int y = 0; y < 256; ++y) {
        acc += row[y] * tw[idx];
        idx = (idx + ky) & 255;
    }
    if (part) acc = -acc;   // e^{-i phi}: imag = -sum h*sin
    gy[(((size_t)blockIdx.x * 8 + r) * 16 + ky) * 2 + part] = acc;
}

// ---------------------------------------------------------------------------
// Forward DFT along x: X[bi,kx,ky] = (1/256) * sum_x Gy[bi,x,ky] * e^{-i 2pi kx x/256}
// grid 256 (one per bi = b*32+i), block 256 (thread = kx*16+ky)
// X layout: (bi, kx, ky, part)
// ---------------------------------------------------------------------------
__global__ void k_fwd_x(const float* __restrict__ gy, float* __restrict__ Xf) {
    __shared__ float g[256 * 32];       // (x, ky, part)
    __shared__ float ct[256], st[256];
    int tid = threadIdx.x;
    {
        float ang = (float)tid * TWO_PI_OVER_N;
        ct[tid] = cosf(ang);
        st[tid] = sinf(ang);
    }
    size_t base = (size_t)blockIdx.x * 8192;
#pragma unroll
    for (int j = 0; j < 32; ++j) g[j * 256 + tid] = gy[base + j * 256 + tid];
    __syncthreads();

    int kx = tid >> 4, ky = tid & 15;
    float ar = 0.f, ai = 0.f;
    int idx = 0;
#pragma unroll 4
    for (int x = 0; x < 256; ++x) {
        float c = ct[idx], s = st[idx];
        float gr = g[x * 32 + ky * 2], gi = g[x * 32 + ky * 2 + 1];
        ar += gr * c + gi * s;          // (gr+i gi)(c - i s)
        ai += gi * c - gr * s;
        idx = (idx + kx) & 255;
    }
    Xf[((size_t)blockIdx.x * 256 + tid) * 2 + 0] = ar * (1.0f / 256.0f);
    Xf[((size_t)blockIdx.x * 256 + tid) * 2 + 1] = ai * (1.0f / 256.0f);
}

// ---------------------------------------------------------------------------
// Mode mix: T[b,o,kx,ky] = sum_i X[b,i,kx,ky] * (wr + i wi)[i,o,kx,ky]
// grid 32 (o), block 256 (t = kx*16+ky)
// T layout: (b, o, t, part)
// ---------------------------------------------------------------------------
__global__ void k_mix(const float* __restrict__ Xf, const float* __restrict__ wr,
                      const float* __restrict__ wi, float* __restrict__ Tf) {
    int o = blockIdx.x, t = threadIdx.x;
    float arr[8], aii[8];
#pragma unroll
    for (int b = 0; b < 8; ++b) { arr[b] = 0.f; aii[b] = 0.f; }
    for (int i = 0; i < 32; ++i) {
        float wrv = wr[(size_t)(i * 32 + o) * 256 + t];
        float wiv = wi[(size_t)(i * 32 + o) * 256 + t];
#pragma unroll
        for (int b = 0; b < 8; ++b) {
            float xr = Xf[((size_t)(b * 32 + i) * 256 + t) * 2 + 0];
            float xi = Xf[((size_t)(b * 32 + i) * 256 + t) * 2 + 1];
            arr[b] += xr * wrv - xi * wiv;
            aii[b] += xr * wiv + xi * wrv;
        }
    }
#pragma unroll
    for (int b = 0; b < 8; ++b) {
        Tf[((size_t)(b * 32 + o) * 256 + t) * 2 + 0] = arr[b];
        Tf[((size_t)(b * 32 + o) * 256 + t) * 2 + 1] = aii[b];
    }
}

// ---------------------------------------------------------------------------
// Inverse DFT along x: G'[bo,x,ky] = sum_kx T[bo,kx,ky] * e^{+i 2pi kx x/256}
// grid 256 (bo = b*32+o), block 256 (x)
// gi layout: (b, x, o, ky, part)   -> coalesced consumption in k_update
// ---------------------------------------------------------------------------
__global__ void k_inv_x(const float* __restrict__ Tf, float* __restrict__ gi) {
    __shared__ float tl[512];
    __shared__ float ct[256], st[256];
    int tid = threadIdx.x;
    {
        float ang = (float)tid * TWO_PI_OVER_N;
        ct[tid] = cosf(ang);
        st[tid] = sinf(ang);
    }
    size_t base = (size_t)blockIdx.x * 512;
    tl[tid] = Tf[base + tid];
    tl[256 + tid] = Tf[base + 256 + tid];
    __syncthreads();

    int x = tid;
    float gre[16], gim[16];
#pragma unroll
    for (int ky = 0; ky < 16; ++ky) { gre[ky] = 0.f; gim[ky] = 0.f; }
#pragma unroll
    for (int kx = 0; kx < 16; ++kx) {
        int idx = (kx * x) & 255;
        float c = ct[idx], s = st[idx];
#pragma unroll
        for (int ky = 0; ky < 16; ++ky) {
            float tr = tl[(kx * 16 + ky) * 2 + 0];
            float ti = tl[(kx * 16 + ky) * 2 + 1];
            gre[ky] += tr * c - ti * s;   // (tr+i ti)(c + i s)
            gim[ky] += ti * c + tr * s;
        }
    }
    int b = blockIdx.x >> 5, o = blockIdx.x & 31;
    size_t ob = (((size_t)b * 256 + x) * 32 + o) * 32;
#pragma unroll
    for (int ky = 0; ky < 16; ++ky) {
        gi[ob + ky * 2 + 0] = gre[ky];
        gi[ob + ky * 2 + 1] = gim[ky];
    }
}

// ---------------------------------------------------------------------------
// Fused: inverse DFT along y (c2r semantics) + pointwise conv + GELU + residual
// sc[b,o,x,y] = (1/256) * [ G'[..,0].re  +  2*sum_{ky=1..15} Re(G' e^{+i 2pi ky y/256}) ]
// h = h + gelu(sc + pw_w @ h + pw_b)
// grid 2048 (b*256+x), block 256 (y)
// ---------------------------------------------------------------------------
__global__ void k_update(float* __restrict__ h, const float* __restrict__ gi,
                         const float* __restrict__ pww, const float* __restrict__ pwb) {
    __shared__ float hrow[32 * 256];   // 32 KB
    __shared__ float gt[1024];         // (o, ky, part) 4 KB
    __shared__ float ws[1024];         // pw_w[o][i]    4 KB
    __shared__ float bs[32];
    __shared__ float ct[256], st[256];
    int tid = threadIdx.x;
    int bx = blockIdx.x;               // b*256 + x
    int b = bx >> 8, x = bx & 255;
    {
        float ang = (float)tid * TWO_PI_OVER_N;
        ct[tid] = cosf(ang);
        st[tid] = sinf(ang);
    }
    size_t hbase = ((size_t)b * 32) << 16;   // + i*65536 + x*256 + y
#pragma unroll
    for (int i = 0; i < 32; ++i)
        hrow[i * 256 + tid] = h[hbase + ((size_t)i << 16) + x * 256 + tid];
#pragma unroll
    for (int j = 0; j < 4; ++j) gt[j * 256 + tid] = gi[(size_t)bx * 1024 + j * 256 + tid];
#pragma unroll
    for (int j = 0; j < 4; ++j) ws[j * 256 + tid] = pww[j * 256 + tid];
    if (tid < 32) bs[tid] = pwb[tid];
    __syncthreads();

    int y = tid;
    float hv[32];
#pragma unroll
    for (int i = 0; i < 32; ++i) hv[i] = hrow[i * 256 + y];
    float cy[16], sy[16];
#pragma unroll
    for (int ky = 0; ky < 16; ++ky) {
        int idx = (ky * y) & 255;
        cy[ky] = ct[idx];
        sy[ky] = st[idx];
    }
#pragma unroll 4
    for (int o = 0; o < 32; ++o) {
        // ky = 0 term gets half weight (alpha(0)=1, others 2), times 2/256 at the end
        float sc = 0.5f * (gt[o * 32 + 0] * cy[0] - gt[o * 32 + 1] * sy[0]);
#pragma unroll
        for (int ky = 1; ky < 16; ++ky)
            sc += gt[o * 32 + ky * 2] * cy[ky] - gt[o * 32 + ky * 2 + 1] * sy[ky];
        sc *= (2.0f / 256.0f);
        float pw = bs[o];
#pragma unroll
        for (int i = 0; i < 32; ++i) pw += hv[i] * ws[o * 32 + i];
        float u = sc + pw;
        float outv = hv[o] + gelu_f(u);
        h[hbase + ((size_t)o << 16) + x * 256 + y] = outv;
    }
}

// ---------------------------------------------------------------------------
// Decoder: 3 independent MLP heads (32 -> 32 -> 128 -> 1, exact GELU)
// grid 2048, block 256 (thread per (b,x,y) point)
// ---------------------------------------------------------------------------
__global__ void k_decode(const float* __restrict__ h,
                         const float* __restrict__ w1, const float* __restrict__ b1,
                         const float* __restrict__ w2, const float* __restrict__ b2,
                         const float* __restrict__ w3, const float* __restrict__ b3,
                         float* __restrict__ out) {
    __shared__ float w1s[1024];    // [i][o]
    __shared__ float w2s[4096];    // [i][j]
    __shared__ float w3s[128];
    __shared__ float b1s[32];
    __shared__ float b2s[128];
    int tid = threadIdx.x;
    int g = blockIdx.x * 256 + tid;
    int b = g >> 16, pos = g & 65535;
    float hf[32];
#pragma unroll
    for (int i = 0; i < 32; ++i) hf[i] = h[((size_t)(b * 32 + i) << 16) + pos];

    for (int d = 0; d < 3; ++d) {
        __syncthreads();
#pragma unroll
        for (int j = 0; j < 4; ++j) w1s[j * 256 + tid] = w1[d * 1024 + j * 256 + tid];
#pragma unroll
        for (int j = 0; j < 16; ++j) w2s[j * 256 + tid] = w2[d * 4096 + j * 256 + tid];
        if (tid < 128) { w3s[tid] = w3[d * 128 + tid]; b2s[tid] = b2[d * 128 + tid]; }
        if (tid < 32) b1s[tid] = b1[d * 32 + tid];
        __syncthreads();

        float z1[32];
#pragma unroll 4
        for (int o = 0; o < 32; ++o) {
            float a = b1s[o];
#pragma unroll
            for (int i = 0; i < 32; ++i) a += hf[i] * w1s[i * 32 + o];
            z1[o] = gelu_f(a);
        }
        float z3 = b3[d];
#pragma unroll 4
        for (int j = 0; j < 128; ++j) {
            float a = b2s[j];
#pragma unroll
            for (int i = 0; i < 32; ++i) a += z1[i] * w2s[i * 128 + j];
            z3 += gelu_f(a) * w3s[j];
        }
        out[(size_t)g * 3 + d] = z3;
    }
}

// ---------------------------------------------------------------------------
extern "C" void kernel_launch(void* const* d_in, const int* in_sizes, int n_in,
                              void* d_out, int out_size, void* d_ws, size_t ws_size,
                              hipStream_t stream) {
    const float* bc      = (const float*)d_in[0];
    const float* xg      = (const float*)d_in[1];
    const float* yg      = (const float*)d_in[2];
    const float* mlp1_w  = (const float*)d_in[3];
    const float* mlp1_b  = (const float*)d_in[4];
    const float* spec_wr = (const float*)d_in[5];
    const float* spec_wi = (const float*)d_in[6];
    const float* pw_w    = (const float*)d_in[7];
    const float* pw_b    = (const float*)d_in[8];
    const float* dec_w1  = (const float*)d_in[9];
    const float* dec_b1  = (const float*)d_in[10];
    const float* dec_w2  = (const float*)d_in[11];
    const float* dec_b2  = (const float*)d_in[12];
    const float* dec_w3  = (const float*)d_in[13];
    const float* dec_b3  = (const float*)d_in[14];
    float* out = (float*)d_out;

    float* h  = (float*)d_ws;                 // 16,777,216 floats (64 MB)
    float* gy = h + 16777216;                 //  2,097,152 floats (8 MB)
    float* Xf = gy + 2097152;                 //    131,072 floats (0.5 MB)
    float* Tf = Xf + 131072;                  //    131,072 floats
    float* gi = Tf + 131072;                  //  2,097,152 floats (8 MB)
    (void)ws_size; (void)n_in; (void)in_sizes; (void)out_size;

    k_lift<<<2048, 256, 0, stream>>>(bc, xg, yg, mlp1_w, mlp1_b, h);
    for (int l = 0; l < NL; ++l) {
        k_fwd_y<<<8192, 256, 0, stream>>>(h, gy);
        k_fwd_x<<<256, 256, 0, stream>>>(gy, Xf);
        k_mix<<<32, 256, 0, stream>>>(Xf, spec_wr + (size_t)l * 262144,
                                      spec_wi + (size_t)l * 262144, Tf);
        k_inv_x<<<256, 256, 0, stream>>>(Tf, gi);
        k_update<<<2048, 256, 0, stream>>>(h, gi, pw_w + l * 1024, pw_b + l * 32);
    }
    k_decode<<<2048, 256, 0, stream>>>(h, dec_w1, dec_b1, dec_w2, dec_b2,
                                       dec_w3, dec_b3, out);
}

// Round 3
// 1160.569 us; speedup vs baseline: 1.2256x; 1.2256x over previous
//
#include <hip/hip_runtime.h>
#include <math.h>

// Problem constants
#define BSZ 8
#define CW  32      // WIDTH (channels)
#define NN  256     // NX = NY
#define MM  16      // modes M1 = M2
#define NL  4
#define HID 128

static __device__ __forceinline__ float gelu_f(float v) {
    return 0.5f * v * (1.0f + erff(v * 0.70710678118654752f));
}

#define TWO_PI_OVER_N (6.28318530717958647692f / 256.0f)

// ---------------------------------------------------------------------------
// Build forward-DFT twiddle matrix Wf[y][2*ky+p]: p=0 -> cos, p=1 -> -sin
// ---------------------------------------------------------------------------
__global__ void k_twiddle(float* __restrict__ Wf) {
    int idx = blockIdx.x * 256 + threadIdx.x;   // 8192 = 256 y * 32 c
    int y = idx >> 5, c = idx & 31;
    int ky = c >> 1, p = c & 1;
    int m = (ky * y) & 255;
    float ang = (float)m * TWO_PI_OVER_N;
    Wf[idx] = p ? -sinf(ang) : cosf(ang);
}

// ---------------------------------------------------------------------------
// Transpose decoder weights: w1t[d][o][i] <- w1[d][i][o]; w2t[d][j][i] <- w2[d][i][j]
// ---------------------------------------------------------------------------
__global__ void k_prep_dec(const float* __restrict__ w1, const float* __restrict__ w2,
                           float* __restrict__ w1t, float* __restrict__ w2t) {
    int tid = threadIdx.x;
    for (int idx = tid; idx < 3 * 32 * 32; idx += 256) {
        int d = idx >> 10, r = idx & 1023, o = r >> 5, i = r & 31;
        w1t[idx] = w1[d * 1024 + i * 32 + o];
    }
    for (int idx = tid; idx < 3 * 128 * 32; idx += 256) {
        int d = idx >> 12, r = idx & 4095, j = r >> 5, i = r & 31;
        w2t[idx] = w2[d * 4096 + i * 128 + j];
    }
}

// ---------------------------------------------------------------------------
// Lifting
// ---------------------------------------------------------------------------
__global__ void k_lift(const float* __restrict__ bc, const float* __restrict__ xg,
                       const float* __restrict__ yg, const float* __restrict__ w,
                       const float* __restrict__ bias, float* __restrict__ h) {
    int idx = blockIdx.x * 256 + threadIdx.x;   // over B*N*N
    int b = idx >> 16, pos = idx & 65535;
    float i0 = bc[b * 3 + 0], i1 = bc[b * 3 + 1], i2 = bc[b * 3 + 2];
    float i3 = xg[idx], i4 = yg[idx];
#pragma unroll
    for (int c = 0; c < CW; ++c) {
        float v = i0 * w[c] + i1 * w[CW + c] + i2 * w[2 * CW + c]
                + i3 * w[3 * CW + c] + i4 * w[4 * CW + c] + bias[c];
        h[((size_t)(b * CW + c) << 16) + pos] = v;
    }
}

// ---------------------------------------------------------------------------
// Forward DFT along y as GEMM vs Wf. Block: 4 waves; wave wv owns y-quarter,
// lane l owns row blockIdx*64+l. Wf wave-uniform -> s_load. LDS reduce.
// gy layout: (row, c) with c = 2*ky+part
// ---------------------------------------------------------------------------
__global__ void k_fwd_y(const float* __restrict__ h, const float* __restrict__ Wf,
                        float* __restrict__ gy) {
    __shared__ float red[4][64][33];   // padded
    int tid = threadIdx.x;
    int wv = tid >> 6, lane = tid & 63;
    int row0 = blockIdx.x * 64;
    const float* hp = h + (size_t)(row0 + lane) * 256 + wv * 64;
    const float* wp = Wf + wv * 64 * 32;
    float acc[32];
#pragma unroll
    for (int c = 0; c < 32; ++c) acc[c] = 0.f;
#pragma unroll 4
    for (int yy = 0; yy < 64; yy += 4) {
        float4 hv = *(const float4*)(hp + yy);
        const float* wr0 = wp + yy * 32;
#pragma unroll
        for (int c = 0; c < 32; ++c) acc[c] += hv.x * wr0[c];
#pragma unroll
        for (int c = 0; c < 32; ++c) acc[c] += hv.y * wr0[32 + c];
#pragma unroll
        for (int c = 0; c < 32; ++c) acc[c] += hv.z * wr0[64 + c];
#pragma unroll
        for (int c = 0; c < 32; ++c) acc[c] += hv.w * wr0[96 + c];
    }
#pragma unroll
    for (int c = 0; c < 32; ++c) red[wv][lane][c] = acc[c];
    __syncthreads();
#pragma unroll
    for (int k = 0; k < 8; ++k) {
        int o = k * 256 + tid;          // 0..2047
        int r = o >> 5, c = o & 31;
        float v = red[0][r][c] + red[1][r][c] + red[2][r][c] + red[3][r][c];
        gy[(size_t)(row0 + r) * 32 + c] = v;
    }
}

// ---------------------------------------------------------------------------
// Forward DFT along x
// ---------------------------------------------------------------------------
__global__ void k_fwd_x(const float* __restrict__ gy, float* __restrict__ Xf) {
    __shared__ float g[256 * 32];
    __shared__ float ct[256], st[256];
    int tid = threadIdx.x;
    {
        float ang = (float)tid * TWO_PI_OVER_N;
        ct[tid] = cosf(ang);
        st[tid] = sinf(ang);
    }
    size_t base = (size_t)blockIdx.x * 8192;
#pragma unroll
    for (int j = 0; j < 32; ++j) g[j * 256 + tid] = gy[base + j * 256 + tid];
    __syncthreads();

    int kx = tid >> 4, ky = tid & 15;
    float ar = 0.f, ai = 0.f;
    int idx = 0;
#pragma unroll 4
    for (int x = 0; x < 256; ++x) {
        float c = ct[idx], s = st[idx];
        float gr = g[x * 32 + ky * 2], gi = g[x * 32 + ky * 2 + 1];
        ar += gr * c + gi * s;
        ai += gi * c - gr * s;
        idx = (idx + kx) & 255;
    }
    Xf[((size_t)blockIdx.x * 256 + tid) * 2 + 0] = ar * (1.0f / 256.0f);
    Xf[((size_t)blockIdx.x * 256 + tid) * 2 + 1] = ai * (1.0f / 256.0f);
}

// ---------------------------------------------------------------------------
// Mode mix
// ---------------------------------------------------------------------------
__global__ void k_mix(const float* __restrict__ Xf, const float* __restrict__ wr,
                      const float* __restrict__ wi, float* __restrict__ Tf) {
    int o = blockIdx.x, t = threadIdx.x;
    float arr[8], aii[8];
#pragma unroll
    for (int b = 0; b < 8; ++b) { arr[b] = 0.f; aii[b] = 0.f; }
    for (int i = 0; i < 32; ++i) {
        float wrv = wr[(size_t)(i * 32 + o) * 256 + t];
        float wiv = wi[(size_t)(i * 32 + o) * 256 + t];
#pragma unroll
        for (int b = 0; b < 8; ++b) {
            float xr = Xf[((size_t)(b * 32 + i) * 256 + t) * 2 + 0];
            float xi = Xf[((size_t)(b * 32 + i) * 256 + t) * 2 + 1];
            arr[b] += xr * wrv - xi * wiv;
            aii[b] += xr * wiv + xi * wrv;
        }
    }
#pragma unroll
    for (int b = 0; b < 8; ++b) {
        Tf[((size_t)(b * 32 + o) * 256 + t) * 2 + 0] = arr[b];
        Tf[((size_t)(b * 32 + o) * 256 + t) * 2 + 1] = aii[b];
    }
}

// ---------------------------------------------------------------------------
// Inverse DFT along x: T wave-uniform -> s_load; twiddles from LDS table.
// gi layout: (b, x, o, ky, part)
// ---------------------------------------------------------------------------
__global__ void k_inv_x(const float* __restrict__ Tf, float* __restrict__ gi) {
    __shared__ float ct[256], st[256];
    int tid = threadIdx.x;
    {
        float ang = (float)tid * TWO_PI_OVER_N;
        ct[tid] = cosf(ang);
        st[tid] = sinf(ang);
    }
    __syncthreads();

    int x = tid;
    const float* tp = Tf + (size_t)blockIdx.x * 512;
    float gre[16], gim[16];
#pragma unroll
    for (int ky = 0; ky < 16; ++ky) { gre[ky] = 0.f; gim[ky] = 0.f; }
#pragma unroll 4
    for (int kx = 0; kx < 16; ++kx) {
        int idx = (kx * x) & 255;
        float c = ct[idx], s = st[idx];
        const float* tk = tp + kx * 32;     // uniform -> s_load
#pragma unroll
        for (int ky = 0; ky < 16; ++ky) {
            float tr = tk[ky * 2 + 0];
            float ti = tk[ky * 2 + 1];
            gre[ky] += tr * c - ti * s;
            gim[ky] += ti * c + tr * s;
        }
    }
    int b = blockIdx.x >> 5, o = blockIdx.x & 31;
    size_t ob = (((size_t)b * 256 + x) * 32 + o) * 32;
#pragma unroll
    for (int ky = 0; ky < 16; ++ky) {
        gi[ob + ky * 2 + 0] = gre[ky];
        gi[ob + ky * 2 + 1] = gim[ky];
    }
}

// ---------------------------------------------------------------------------
// Fused inverse-y DFT (c2r) + pointwise + GELU + residual
// ---------------------------------------------------------------------------
__global__ void k_update(float* __restrict__ h, const float* __restrict__ gi,
                         const float* __restrict__ pww, const float* __restrict__ pwb) {
    __shared__ float ct[256], st[256];
    int tid = threadIdx.x;
    int bx = blockIdx.x;               // b*256 + x
    int b = bx >> 8, x = bx & 255;
    {
        float ang = (float)tid * TWO_PI_OVER_N;
        ct[tid] = cosf(ang);
        st[tid] = sinf(ang);
    }
    __syncthreads();

    int y = tid;
    size_t hbase = ((size_t)b * 32) << 16;
    float hv[32];
#pragma unroll
    for (int i = 0; i < 32; ++i) hv[i] = h[hbase + ((size_t)i << 16) + x * 256 + y];
    float cy[16], sy[16];
#pragma unroll
    for (int ky = 0; ky < 16; ++ky) {
        int m = (ky * y) & 255;
        cy[ky] = ct[m];
        sy[ky] = st[m];
    }
    const float* gp = gi + (size_t)bx * 1024;
#pragma unroll 4
    for (int o = 0; o < 32; ++o) {
        const float* go = gp + o * 32;       // uniform -> s_load
        float sc = 0.5f * go[0];             // cy[0]=1, sy[0]=0
#pragma unroll
        for (int ky = 1; ky < 16; ++ky)
            sc += go[ky * 2] * cy[ky] - go[ky * 2 + 1] * sy[ky];
        sc *= (2.0f / 256.0f);
        const float* wo = pww + o * 32;      // uniform -> s_load
        float pw = pwb[o];
#pragma unroll
        for (int i = 0; i < 32; ++i) pw += hv[i] * wo[i];
        float u = sc + pw;
        h[hbase + ((size_t)o << 16) + x * 256 + y] = hv[o] + gelu_f(u);
    }
}

// ---------------------------------------------------------------------------
// Decoder with pre-transposed weights (s_load rows of 32)
// ---------------------------------------------------------------------------
__global__ void k_decode(const float* __restrict__ h,
                         const float* __restrict__ w1t, const float* __restrict__ b1,
                         const float* __restrict__ w2t, const float* __restrict__ b2,
                         const float* __restrict__ w3, const float* __restrict__ b3,
                         float* __restrict__ out) {
    int g = blockIdx.x * 256 + threadIdx.x;
    int b = g >> 16, pos = g & 65535;
    float hf[32];
#pragma unroll
    for (int i = 0; i < 32; ++i) hf[i] = h[((size_t)(b * 32 + i) << 16) + pos];
    float res[3];
    for (int d = 0; d < 3; ++d) {
        float z1[32];
        const float* w1p = w1t + d * 1024;
#pragma unroll 4
        for (int o = 0; o < 32; ++o) {
            const float* wrow = w1p + o * 32;    // uniform -> s_load
            float a = b1[d * 32 + o];
#pragma unroll
            for (int i = 0; i < 32; ++i) a += hf[i] * wrow[i];
            z1[o] = gelu_f(a);
        }
        float z3 = b3[d];
        const float* w2p = w2t + d * 4096;
#pragma unroll 2
        for (int j = 0; j < 128; ++j) {
            const float* wrow = w2p + j * 32;    // uniform -> s_load
            float a = b2[d * 128 + j];
#pragma unroll
            for (int i = 0; i < 32; ++i) a += z1[i] * wrow[i];
            z3 += gelu_f(a) * w3[d * 128 + j];
        }
        res[d] = z3;
    }
    out[(size_t)g * 3 + 0] = res[0];
    out[(size_t)g * 3 + 1] = res[1];
    out[(size_t)g * 3 + 2] = res[2];
}

// ---------------------------------------------------------------------------
// Workspace layout (floats). gy and gi share one region: gy is dead after
// k_fwd_x, gi is born at k_inv_x (disjoint lifetimes, identical size).
// Total = 19,160,064 floats = 76.6 MB  (< 84.9 MB proven safe in round 1).
// ---------------------------------------------------------------------------
extern "C" void kernel_launch(void* const* d_in, const int* in_sizes, int n_in,
                              void* d_out, int out_size, void* d_ws, size_t ws_size,
                              hipStream_t stream) {
    const float* bc      = (const float*)d_in[0];
    const float* xg      = (const float*)d_in[1];
    const float* yg      = (const float*)d_in[2];
    const float* mlp1_w  = (const float*)d_in[3];
    const float* mlp1_b  = (const float*)d_in[4];
    const float* spec_wr = (const float*)d_in[5];
    const float* spec_wi = (const float*)d_in[6];
    const float* pw_w    = (const float*)d_in[7];
    const float* pw_b    = (const float*)d_in[8];
    const float* dec_w1  = (const float*)d_in[9];
    const float* dec_b1  = (const float*)d_in[10];
    const float* dec_w2  = (const float*)d_in[11];
    const float* dec_b2  = (const float*)d_in[12];
    const float* dec_w3  = (const float*)d_in[13];
    const float* dec_b3  = (const float*)d_in[14];
    float* out = (float*)d_out;

    float* h    = (float*)d_ws;               // 16,777,216 floats
    float* spec = h + 16777216;               //  2,097,152 (shared gy / gi)
    float* Xf   = spec + 2097152;             //    131,072
    float* Tf   = Xf + 131072;                //    131,072
    float* Wf   = Tf + 131072;                //      8,192
    float* w1t  = Wf + 8192;                  //      3,072
    float* w2t  = w1t + 3072;                 //     12,288
    float* gy   = spec;
    float* gi   = spec;
    (void)ws_size; (void)n_in; (void)in_sizes; (void)out_size;

    k_twiddle<<<32, 256, 0, stream>>>(Wf);
    k_prep_dec<<<1, 256, 0, stream>>>(dec_w1, dec_w2, w1t, w2t);
    k_lift<<<2048, 256, 0, stream>>>(bc, xg, yg, mlp1_w, mlp1_b, h);
    for (int l = 0; l < NL; ++l) {
        k_fwd_y<<<1024, 256, 0, stream>>>(h, Wf, gy);
        k_fwd_x<<<256, 256, 0, stream>>>(gy, Xf);
        k_mix<<<32, 256, 0, stream>>>(Xf, spec_wr + (size_t)l * 262144,
                                      spec_wi + (size_t)l * 262144, Tf);
        k_inv_x<<<256, 256, 0, stream>>>(Tf, gi);
        k_update<<<2048, 256, 0, stream>>>(h, gi, pw_w + l * 1024, pw_b + l * 32);
    }
    k_decode<<<2048, 256, 0, stream>>>(h, w1t, dec_b1, w2t, dec_b2,
                                       dec_w3, dec_b3, out);
}

// Round 4
// 1058.565 us; speedup vs baseline: 1.3437x; 1.0964x over previous
//
#include <hip/hip_runtime.h>
#include <math.h>

// Problem constants
#define BSZ 8
#define CW  32      // WIDTH (channels)
#define NN  256     // NX = NY
#define MM  16      // modes M1 = M2
#define NL  4
#define HID 128

// ---------------------------------------------------------------------------
// Fast exact-erf GELU: Abramowitz-Stegun 7.1.26 (max |err| 1.5e-7), branchless.
// gelu(v) = 0.5 v (1 + erf(v/sqrt2)) = 0.5 v + 0.5 |v| erf(|v|/sqrt2)
// ~14 VALU ops incl. hardware v_rcp_f32 + v_exp_f32 (vs ~30+ divergent libm erff)
// ---------------------------------------------------------------------------
static __device__ __forceinline__ float gelu_f(float v) {
    float au = fabsf(v) * 0.70710678118654752f;
    float t  = __builtin_amdgcn_rcpf(fmaf(0.3275911f, au, 1.0f));
    float p  = fmaf(fmaf(fmaf(fmaf(1.061405429f, t, -1.453152027f),
                              t, 1.421413741f),
                         t, -0.284496736f),
                    t, 0.254829592f) * t;
    float e  = __expf(-au * au);
    float E  = fmaf(-p, e, 1.0f);          // erf(|v|/sqrt2)
    return fmaf(0.5f * fabsf(v), E, 0.5f * v);
}

#define TWO_PI_OVER_N (6.28318530717958647692f / 256.0f)

// ---------------------------------------------------------------------------
// Build forward-DFT twiddle matrix Wf[y][2*ky+p]: p=0 -> cos, p=1 -> -sin
// ---------------------------------------------------------------------------
__global__ void k_twiddle(float* __restrict__ Wf) {
    int idx = blockIdx.x * 256 + threadIdx.x;   // 8192 = 256 y * 32 c
    int y = idx >> 5, c = idx & 31;
    int ky = c >> 1, p = c & 1;
    int m = (ky * y) & 255;
    float ang = (float)m * TWO_PI_OVER_N;
    Wf[idx] = p ? -sinf(ang) : cosf(ang);
}

// ---------------------------------------------------------------------------
// Transpose decoder weights: w1t[d][o][i] <- w1[d][i][o]; w2t[d][j][i] <- w2[d][i][j]
// ---------------------------------------------------------------------------
__global__ void k_prep_dec(const float* __restrict__ w1, const float* __restrict__ w2,
                           float* __restrict__ w1t, float* __restrict__ w2t) {
    int tid = threadIdx.x;
    for (int idx = tid; idx < 3 * 32 * 32; idx += 256) {
        int d = idx >> 10, r = idx & 1023, o = r >> 5, i = r & 31;
        w1t[idx] = w1[d * 1024 + i * 32 + o];
    }
    for (int idx = tid; idx < 3 * 128 * 32; idx += 256) {
        int d = idx >> 12, r = idx & 4095, j = r >> 5, i = r & 31;
        w2t[idx] = w2[d * 4096 + i * 128 + j];
    }
}

// ---------------------------------------------------------------------------
// Lifting
// ---------------------------------------------------------------------------
__global__ void k_lift(const float* __restrict__ bc, const float* __restrict__ xg,
                       const float* __restrict__ yg, const float* __restrict__ w,
                       const float* __restrict__ bias, float* __restrict__ h) {
    int idx = blockIdx.x * 256 + threadIdx.x;   // over B*N*N
    int b = idx >> 16, pos = idx & 65535;
    float i0 = bc[b * 3 + 0], i1 = bc[b * 3 + 1], i2 = bc[b * 3 + 2];
    float i3 = xg[idx], i4 = yg[idx];
#pragma unroll
    for (int c = 0; c < CW; ++c) {
        float v = i0 * w[c] + i1 * w[CW + c] + i2 * w[2 * CW + c]
                + i3 * w[3 * CW + c] + i4 * w[4 * CW + c] + bias[c];
        h[((size_t)(b * CW + c) << 16) + pos] = v;
    }
}

// ---------------------------------------------------------------------------
// Forward DFT along y as GEMM vs Wf. Block: 4 waves; wave wv owns y-quarter,
// lane l owns row blockIdx*64+l. Wf wave-uniform -> s_load. LDS reduce.
// gy layout: (row, c) with c = 2*ky+part
// ---------------------------------------------------------------------------
__global__ void k_fwd_y(const float* __restrict__ h, const float* __restrict__ Wf,
                        float* __restrict__ gy) {
    __shared__ float red[4][64][33];   // padded
    int tid = threadIdx.x;
    int wv = tid >> 6, lane = tid & 63;
    int row0 = blockIdx.x * 64;
    const float* hp = h + (size_t)(row0 + lane) * 256 + wv * 64;
    const float* wp = Wf + wv * 64 * 32;
    float acc[32];
#pragma unroll
    for (int c = 0; c < 32; ++c) acc[c] = 0.f;
#pragma unroll 4
    for (int yy = 0; yy < 64; yy += 4) {
        float4 hv = *(const float4*)(hp + yy);
        const float* wr0 = wp + yy * 32;
#pragma unroll
        for (int c = 0; c < 32; ++c) acc[c] += hv.x * wr0[c];
#pragma unroll
        for (int c = 0; c < 32; ++c) acc[c] += hv.y * wr0[32 + c];
#pragma unroll
        for (int c = 0; c < 32; ++c) acc[c] += hv.z * wr0[64 + c];
#pragma unroll
        for (int c = 0; c < 32; ++c) acc[c] += hv.w * wr0[96 + c];
    }
#pragma unroll
    for (int c = 0; c < 32; ++c) red[wv][lane][c] = acc[c];
    __syncthreads();
#pragma unroll
    for (int k = 0; k < 8; ++k) {
        int o = k * 256 + tid;          // 0..2047
        int r = o >> 5, c = o & 31;
        float v = red[0][r][c] + red[1][r][c] + red[2][r][c] + red[3][r][c];
        gy[(size_t)(row0 + r) * 32 + c] = v;
    }
}

// ---------------------------------------------------------------------------
// Forward DFT along x
// ---------------------------------------------------------------------------
__global__ void k_fwd_x(const float* __restrict__ gy, float* __restrict__ Xf) {
    __shared__ float g[256 * 32];
    __shared__ float ct[256], st[256];
    int tid = threadIdx.x;
    {
        float ang = (float)tid * TWO_PI_OVER_N;
        ct[tid] = cosf(ang);
        st[tid] = sinf(ang);
    }
    size_t base = (size_t)blockIdx.x * 8192;
#pragma unroll
    for (int j = 0; j < 32; ++j) g[j * 256 + tid] = gy[base + j * 256 + tid];
    __syncthreads();

    int kx = tid >> 4, ky = tid & 15;
    float ar = 0.f, ai = 0.f;
    int idx = 0;
#pragma unroll 4
    for (int x = 0; x < 256; ++x) {
        float c = ct[idx], s = st[idx];
        float gr = g[x * 32 + ky * 2], gi = g[x * 32 + ky * 2 + 1];
        ar += gr * c + gi * s;
        ai += gi * c - gr * s;
        idx = (idx + kx) & 255;
    }
    Xf[((size_t)blockIdx.x * 256 + tid) * 2 + 0] = ar * (1.0f / 256.0f);
    Xf[((size_t)blockIdx.x * 256 + tid) * 2 + 1] = ai * (1.0f / 256.0f);
}

// ---------------------------------------------------------------------------
// Fused mode-mix + inverse x-DFT.  Block = (b,o), grid 256, threads 256.
// Phase 1 (thread = t = kx*16+ky): T[t] = sum_i X[b,i,t] * W[i,o,t]  -> LDS
//   (weight reads coalesced in t; X read as float2, L2-resident)
// Phase 2 (thread = x): G'[b,x,o,ky] = sum_kx T[kx,ky] e^{+i 2pi kx x/256}
//   (T reads uniform -> LDS broadcast, free)
// gi layout: (b, x, o, ky, part)
// ---------------------------------------------------------------------------
__global__ void k_spec(const float* __restrict__ Xf, const float* __restrict__ wr,
                       const float* __restrict__ wi, float* __restrict__ gi) {
    __shared__ float tl[512];
    __shared__ float ct[256], st[256];
    int tid = threadIdx.x;
    {
        float ang = (float)tid * TWO_PI_OVER_N;
        ct[tid] = cosf(ang);
        st[tid] = sinf(ang);
    }
    int b = blockIdx.x >> 5, o = blockIdx.x & 31;

    // phase 1: mix
    float tr = 0.f, ti = 0.f;
    const float2* xp = (const float2*)Xf + (size_t)b * 8192 + tid;  // + i*256
    const float* wrp = wr + (size_t)o * 256 + tid;                  // + i*8192
    const float* wip = wi + (size_t)o * 256 + tid;
#pragma unroll 8
    for (int i = 0; i < 32; ++i) {
        float2 xv = xp[i * 256];
        float wrv = wrp[(size_t)i * 8192];
        float wiv = wip[(size_t)i * 8192];
        tr += xv.x * wrv - xv.y * wiv;
        ti += xv.x * wiv + xv.y * wrv;
    }
    tl[tid * 2 + 0] = tr;
    tl[tid * 2 + 1] = ti;
    __syncthreads();

    // phase 2: inverse x-DFT
    int x = tid;
    float gre[16], gim[16];
#pragma unroll
    for (int ky = 0; ky < 16; ++ky) { gre[ky] = 0.f; gim[ky] = 0.f; }
#pragma unroll 4
    for (int kx = 0; kx < 16; ++kx) {
        int idx = (kx * x) & 255;
        float c = ct[idx], s = st[idx];
#pragma unroll
        for (int ky = 0; ky < 16; ++ky) {
            float t2r = tl[(kx * 16 + ky) * 2 + 0];
            float t2i = tl[(kx * 16 + ky) * 2 + 1];
            gre[ky] += t2r * c - t2i * s;   // (tr + i ti)(c + i s)
            gim[ky] += t2i * c + t2r * s;
        }
    }
    size_t ob = (((size_t)b * 256 + x) * 32 + o) * 32;
#pragma unroll
    for (int ky = 0; ky < 16; ++ky) {
        gi[ob + ky * 2 + 0] = gre[ky];
        gi[ob + ky * 2 + 1] = gim[ky];
    }
}

// ---------------------------------------------------------------------------
// Fused inverse-y DFT (c2r) + pointwise + GELU + residual
// ---------------------------------------------------------------------------
__global__ void k_update(float* __restrict__ h, const float* __restrict__ gi,
                         const float* __restrict__ pww, const float* __restrict__ pwb) {
    __shared__ float ct[256], st[256];
    int tid = threadIdx.x;
    int bx = blockIdx.x;               // b*256 + x
    int b = bx >> 8, x = bx & 255;
    {
        float ang = (float)tid * TWO_PI_OVER_N;
        ct[tid] = cosf(ang);
        st[tid] = sinf(ang);
    }
    __syncthreads();

    int y = tid;
    size_t hbase = ((size_t)b * 32) << 16;
    float hv[32];
#pragma unroll
    for (int i = 0; i < 32; ++i) hv[i] = h[hbase + ((size_t)i << 16) + x * 256 + y];
    float cy[16], sy[16];
#pragma unroll
    for (int ky = 0; ky < 16; ++ky) {
        int m = (ky * y) & 255;
        cy[ky] = ct[m];
        sy[ky] = st[m];
    }
    const float* gp = gi + (size_t)bx * 1024;
#pragma unroll 4
    for (int o = 0; o < 32; ++o) {
        const float* go = gp + o * 32;       // uniform -> s_load
        float sc = 0.5f * go[0];             // cy[0]=1, sy[0]=0
#pragma unroll
        for (int ky = 1; ky < 16; ++ky)
            sc += go[ky * 2] * cy[ky] - go[ky * 2 + 1] * sy[ky];
        sc *= (2.0f / 256.0f);
        const float* wo = pww + o * 32;      // uniform -> s_load
        float pw = pwb[o];
#pragma unroll
        for (int i = 0; i < 32; ++i) pw += hv[i] * wo[i];
        float u = sc + pw;
        h[hbase + ((size_t)o << 16) + x * 256 + y] = hv[o] + gelu_f(u);
    }
}

// ---------------------------------------------------------------------------
// Decoder with pre-transposed weights (s_load rows of 32) + fast GELU
// ---------------------------------------------------------------------------
__global__ void k_decode(const float* __restrict__ h,
                         const float* __restrict__ w1t, const float* __restrict__ b1,
                         const float* __restrict__ w2t, const float* __restrict__ b2,
                         const float* __restrict__ w3, const float* __restrict__ b3,
                         float* __restrict__ out) {
    int g = blockIdx.x * 256 + threadIdx.x;
    int b = g >> 16, pos = g & 65535;
    float hf[32];
#pragma unroll
    for (int i = 0; i < 32; ++i) hf[i] = h[((size_t)(b * 32 + i) << 16) + pos];
    float res[3];
    for (int d = 0; d < 3; ++d) {
        float z1[32];
        const float* w1p = w1t + d * 1024;
#pragma unroll 4
        for (int o = 0; o < 32; ++o) {
            const float* wrow = w1p + o * 32;    // uniform -> s_load
            float a = b1[d * 32 + o];
#pragma unroll
            for (int i = 0; i < 32; ++i) a += hf[i] * wrow[i];
            z1[o] = gelu_f(a);
        }
        float z3 = b3[d];
        const float* w2p = w2t + d * 4096;
#pragma unroll 2
        for (int j = 0; j < 128; ++j) {
            const float* wrow = w2p + j * 32;    // uniform -> s_load
            float a = b2[d * 128 + j];
#pragma unroll
            for (int i = 0; i < 32; ++i) a += z1[i] * wrow[i];
            z3 += gelu_f(a) * w3[d * 128 + j];
        }
        res[d] = z3;
    }
    out[(size_t)g * 3 + 0] = res[0];
    out[(size_t)g * 3 + 1] = res[1];
    out[(size_t)g * 3 + 2] = res[2];
}

// ---------------------------------------------------------------------------
// Workspace (floats): gy and gi share one region (disjoint lifetimes).
// Total = 19,028,992 floats = 76.1 MB (round-3 proven safe at 76.6 MB).
// ---------------------------------------------------------------------------
extern "C" void kernel_launch(void* const* d_in, const int* in_sizes, int n_in,
                              void* d_out, int out_size, void* d_ws, size_t ws_size,
                              hipStream_t stream) {
    const float* bc      = (const float*)d_in[0];
    const float* xg      = (const float*)d_in[1];
    const float* yg      = (const float*)d_in[2];
    const float* mlp1_w  = (const float*)d_in[3];
    const float* mlp1_b  = (const float*)d_in[4];
    const float* spec_wr = (const float*)d_in[5];
    const float* spec_wi = (const float*)d_in[6];
    const float* pw_w    = (const float*)d_in[7];
    const float* pw_b    = (const float*)d_in[8];
    const float* dec_w1  = (const float*)d_in[9];
    const float* dec_b1  = (const float*)d_in[10];
    const float* dec_w2  = (const float*)d_in[11];
    const float* dec_b2  = (const float*)d_in[12];
    const float* dec_w3  = (const float*)d_in[13];
    const float* dec_b3  = (const float*)d_in[14];
    float* out = (float*)d_out;

    float* h    = (float*)d_ws;               // 16,777,216 floats
    float* spec = h + 16777216;               //  2,097,152 (shared gy / gi)
    float* Xf   = spec + 2097152;             //    131,072
    float* Wf   = Xf + 131072;                //      8,192
    float* w1t  = Wf + 8192;                  //      3,072
    float* w2t  = w1t + 3072;                 //     12,288
    float* gy   = spec;
    float* gi   = spec;
    (void)ws_size; (void)n_in; (void)in_sizes; (void)out_size;

    k_twiddle<<<32, 256, 0, stream>>>(Wf);
    k_prep_dec<<<1, 256, 0, stream>>>(dec_w1, dec_w2, w1t, w2t);
    k_lift<<<2048, 256, 0, stream>>>(bc, xg, yg, mlp1_w, mlp1_b, h);
    for (int l = 0; l < NL; ++l) {
        k_fwd_y<<<1024, 256, 0, stream>>>(h, Wf, gy);
        k_fwd_x<<<256, 256, 0, stream>>>(gy, Xf);
        k_spec<<<256, 256, 0, stream>>>(Xf, spec_wr + (size_t)l * 262144,
                                        spec_wi + (size_t)l * 262144, gi);
        k_update<<<2048, 256, 0, stream>>>(h, gi, pw_w + l * 1024, pw_b + l * 32);
    }
    k_decode<<<2048, 256, 0, stream>>>(h, w1t, dec_b1, w2t, dec_b2,
                                       dec_w3, dec_b3, out);
}

// Round 5
// 987.224 us; speedup vs baseline: 1.4408x; 1.0723x over previous
//
#include <hip/hip_runtime.h>
#include <math.h>

// Problem constants
#define BSZ 8
#define CW  32      // WIDTH (channels)
#define NN  256     // NX = NY
#define MM  16      // modes M1 = M2
#define NL  4
#define HID 128

// ---------------------------------------------------------------------------
// Fast exact-erf GELU: Abramowitz-Stegun 7.1.26 (max |err| 1.5e-7), branchless.
// ---------------------------------------------------------------------------
static __device__ __forceinline__ float gelu_f(float v) {
    float au = fabsf(v) * 0.70710678118654752f;
    float t  = __builtin_amdgcn_rcpf(fmaf(0.3275911f, au, 1.0f));
    float p  = fmaf(fmaf(fmaf(fmaf(1.061405429f, t, -1.453152027f),
                              t, 1.421413741f),
                         t, -0.284496736f),
                    t, 0.254829592f) * t;
    float e  = __expf(-au * au);
    float E  = fmaf(-p, e, 1.0f);          // erf(|v|/sqrt2)
    return fmaf(0.5f * fabsf(v), E, 0.5f * v);
}

#define TWO_PI_OVER_N (6.28318530717958647692f / 256.0f)

// ---------------------------------------------------------------------------
// Build forward-DFT twiddle matrix Wf[y][2*ky+p]: p=0 -> cos, p=1 -> -sin
// ---------------------------------------------------------------------------
__global__ void k_twiddle(float* __restrict__ Wf) {
    int idx = blockIdx.x * 256 + threadIdx.x;   // 8192 = 256 y * 32 c
    int y = idx >> 5, c = idx & 31;
    int ky = c >> 1, p = c & 1;
    int m = (ky * y) & 255;
    float ang = (float)m * TWO_PI_OVER_N;
    Wf[idx] = p ? -sinf(ang) : cosf(ang);
}

// ---------------------------------------------------------------------------
// Transpose decoder weights: w1t[d][o][i] <- w1[d][i][o]; w2t[d][j][i] <- w2[d][i][j]
// ---------------------------------------------------------------------------
__global__ void k_prep_dec(const float* __restrict__ w1, const float* __restrict__ w2,
                           float* __restrict__ w1t, float* __restrict__ w2t) {
    int tid = threadIdx.x;
    for (int idx = tid; idx < 3 * 32 * 32; idx += 256) {
        int d = idx >> 10, r = idx & 1023, o = r >> 5, i = r & 31;
        w1t[idx] = w1[d * 1024 + i * 32 + o];
    }
    for (int idx = tid; idx < 3 * 128 * 32; idx += 256) {
        int d = idx >> 12, r = idx & 4095, j = r >> 5, i = r & 31;
        w2t[idx] = w2[d * 4096 + i * 128 + j];
    }
}

// ---------------------------------------------------------------------------
// Lifting
// ---------------------------------------------------------------------------
__global__ void k_lift(const float* __restrict__ bc, const float* __restrict__ xg,
                       const float* __restrict__ yg, const float* __restrict__ w,
                       const float* __restrict__ bias, float* __restrict__ h) {
    int idx = blockIdx.x * 256 + threadIdx.x;   // over B*N*N
    int b = idx >> 16, pos = idx & 65535;
    float i0 = bc[b * 3 + 0], i1 = bc[b * 3 + 1], i2 = bc[b * 3 + 2];
    float i3 = xg[idx], i4 = yg[idx];
#pragma unroll
    for (int c = 0; c < CW; ++c) {
        float v = i0 * w[c] + i1 * w[CW + c] + i2 * w[2 * CW + c]
                + i3 * w[3 * CW + c] + i4 * w[4 * CW + c] + bias[c];
        h[((size_t)(b * CW + c) << 16) + pos] = v;
    }
}

// ---------------------------------------------------------------------------
// Forward DFT along y as GEMM vs Wf. 4 waves; wave wv owns y-quarter,
// lane l owns row blockIdx*64+l. Wf wave-uniform -> s_load. LDS reduce.
// gy layout: (row, c) with c = 2*ky+part
// ---------------------------------------------------------------------------
__global__ void k_fwd_y(const float* __restrict__ h, const float* __restrict__ Wf,
                        float* __restrict__ gy) {
    __shared__ float red[4][64][33];   // padded
    int tid = threadIdx.x;
    int wv = tid >> 6, lane = tid & 63;
    int row0 = blockIdx.x * 64;
    const float* hp = h + (size_t)(row0 + lane) * 256 + wv * 64;
    const float* wp = Wf + wv * 64 * 32;
    float acc[32];
#pragma unroll
    for (int c = 0; c < 32; ++c) acc[c] = 0.f;
#pragma unroll 4
    for (int yy = 0; yy < 64; yy += 4) {
        float4 hv = *(const float4*)(hp + yy);
        const float* wr0 = wp + yy * 32;
#pragma unroll
        for (int c = 0; c < 32; ++c) acc[c] += hv.x * wr0[c];
#pragma unroll
        for (int c = 0; c < 32; ++c) acc[c] += hv.y * wr0[32 + c];
#pragma unroll
        for (int c = 0; c < 32; ++c) acc[c] += hv.z * wr0[64 + c];
#pragma unroll
        for (int c = 0; c < 32; ++c) acc[c] += hv.w * wr0[96 + c];
    }
#pragma unroll
    for (int c = 0; c < 32; ++c) red[wv][lane][c] = acc[c];
    __syncthreads();
#pragma unroll
    for (int k = 0; k < 8; ++k) {
        int o = k * 256 + tid;          // 0..2047
        int r = o >> 5, c = o & 31;
        float v = red[0][r][c] + red[1][r][c] + red[2][r][c] + red[3][r][c];
        gy[(size_t)(row0 + r) * 32 + c] = v;
    }
}

// ---------------------------------------------------------------------------
// Forward DFT along x, 1024 threads: thread = (t = kx*16+ky, xq = tid>>8).
// Each thread sums 64 x values (split-K), LDS-reduce 4 partials.
// ---------------------------------------------------------------------------
__global__ void __launch_bounds__(1024) k_fwd_x(const float* __restrict__ gy,
                                                float* __restrict__ Xf) {
    __shared__ float g[8192];           // (x, c) 32 KB
    __shared__ float part[4][256][2];   // 8 KB
    __shared__ float ct[256], st[256];
    int tid = threadIdx.x;
    if (tid < 256) {
        float ang = (float)tid * TWO_PI_OVER_N;
        ct[tid] = cosf(ang);
        st[tid] = sinf(ang);
    }
    size_t base = (size_t)blockIdx.x * 8192;
#pragma unroll
    for (int j = 0; j < 8; ++j) g[j * 1024 + tid] = gy[base + j * 1024 + tid];
    __syncthreads();

    int t = tid & 255, xq = tid >> 8;
    int kx = t >> 4, ky = t & 15;
    float ar = 0.f, ai = 0.f;
    int x0 = xq * 64;
    int idx = (kx * x0) & 255;
#pragma unroll 4
    for (int x = x0; x < x0 + 64; ++x) {
        float c = ct[idx], s = st[idx];
        float gr = g[x * 32 + ky * 2], gi = g[x * 32 + ky * 2 + 1];
        ar += gr * c + gi * s;          // e^{-i}
        ai += gi * c - gr * s;
        idx = (idx + kx) & 255;
    }
    part[xq][t][0] = ar;
    part[xq][t][1] = ai;
    __syncthreads();
    if (tid < 256) {
        float a0 = part[0][tid][0] + part[1][tid][0] + part[2][tid][0] + part[3][tid][0];
        float a1 = part[0][tid][1] + part[1][tid][1] + part[2][tid][1] + part[3][tid][1];
        Xf[((size_t)blockIdx.x * 256 + tid) * 2 + 0] = a0 * (1.0f / 256.0f);
        Xf[((size_t)blockIdx.x * 256 + tid) * 2 + 1] = a1 * (1.0f / 256.0f);
    }
}

// ---------------------------------------------------------------------------
// Fused mode-mix + inverse x-DFT, 1024 threads. Block = (b,o), grid 256.
// Phase 1: thread (t, ig): partial T over 8 i -> LDS reduce -> tl[512]
// Phase 2: thread (x, kg): 16 kx x 4 ky inverse DFT, direct store.
// gi layout: (b, x, o, ky, part)
// ---------------------------------------------------------------------------
__global__ void __launch_bounds__(1024) k_spec(const float* __restrict__ Xf,
                                               const float* __restrict__ wr,
                                               const float* __restrict__ wi,
                                               float* __restrict__ gi) {
    __shared__ float tl[512];
    __shared__ float pp[4][256][2];
    __shared__ float ct[256], st[256];
    int tid = threadIdx.x;
    if (tid < 256) {
        float ang = (float)tid * TWO_PI_OVER_N;
        ct[tid] = cosf(ang);
        st[tid] = sinf(ang);
    }
    int b = blockIdx.x >> 5, o = blockIdx.x & 31;
    int t = tid & 255, ig = tid >> 8;

    // phase 1: mix (split-K over i)
    float tr = 0.f, ti = 0.f;
    const float2* xp = (const float2*)Xf + (size_t)b * 8192 + t;
    const float* wrp = wr + (size_t)o * 256 + t;
    const float* wip = wi + (size_t)o * 256 + t;
#pragma unroll
    for (int i = ig * 8; i < ig * 8 + 8; ++i) {
        float2 xv = xp[i * 256];
        float wrv = wrp[(size_t)i * 8192];
        float wiv = wip[(size_t)i * 8192];
        tr += xv.x * wrv - xv.y * wiv;
        ti += xv.x * wiv + xv.y * wrv;
    }
    pp[ig][t][0] = tr;
    pp[ig][t][1] = ti;
    __syncthreads();
    if (tid < 256) {
        tl[tid * 2 + 0] = pp[0][tid][0] + pp[1][tid][0] + pp[2][tid][0] + pp[3][tid][0];
        tl[tid * 2 + 1] = pp[0][tid][1] + pp[1][tid][1] + pp[2][tid][1] + pp[3][tid][1];
    }
    __syncthreads();

    // phase 2: inverse x-DFT; thread handles 4 ky for one x
    int x = t, kg = ig;
    float gre[4], gim[4];
#pragma unroll
    for (int k = 0; k < 4; ++k) { gre[k] = 0.f; gim[k] = 0.f; }
#pragma unroll 4
    for (int kx = 0; kx < 16; ++kx) {
        int idx = (kx * x) & 255;
        float c = ct[idx], s = st[idx];
#pragma unroll
        for (int k = 0; k < 4; ++k) {
            int ky = kg * 4 + k;
            float t2r = tl[(kx * 16 + ky) * 2 + 0];
            float t2i = tl[(kx * 16 + ky) * 2 + 1];
            gre[k] += t2r * c - t2i * s;   // e^{+i}
            gim[k] += t2i * c + t2r * s;
        }
    }
    size_t ob = (((size_t)b * 256 + x) * 32 + o) * 32;
#pragma unroll
    for (int k = 0; k < 4; ++k) {
        gi[ob + (kg * 4 + k) * 2 + 0] = gre[k];
        gi[ob + (kg * 4 + k) * 2 + 1] = gim[k];
    }
}

// ---------------------------------------------------------------------------
// Fused inverse-y DFT (c2r) + pointwise + GELU + residual
// launch_bounds(256,4): VGPR cap 128 so hv/cy/sy stay register-resident
// ---------------------------------------------------------------------------
__global__ void __launch_bounds__(256, 4) k_update(float* __restrict__ h,
                         const float* __restrict__ gi,
                         const float* __restrict__ pww, const float* __restrict__ pwb) {
    __shared__ float ct[256], st[256];
    int tid = threadIdx.x;
    int bx = blockIdx.x;               // b*256 + x
    int b = bx >> 8, x = bx & 255;
    {
        float ang = (float)tid * TWO_PI_OVER_N;
        ct[tid] = cosf(ang);
        st[tid] = sinf(ang);
    }
    __syncthreads();

    int y = tid;
    size_t hbase = ((size_t)b * 32) << 16;
    float hv[32];
#pragma unroll
    for (int i = 0; i < 32; ++i) hv[i] = h[hbase + ((size_t)i << 16) + x * 256 + y];
    float cy[16], sy[16];
#pragma unroll
    for (int ky = 0; ky < 16; ++ky) {
        int m = (ky * y) & 255;
        cy[ky] = ct[m];
        sy[ky] = st[m];
    }
    const float* gp = gi + (size_t)bx * 1024;
#pragma unroll 4
    for (int o = 0; o < 32; ++o) {
        const float* go = gp + o * 32;       // uniform -> s_load
        float sc = 0.5f * go[0];             // cy[0]=1, sy[0]=0
#pragma unroll
        for (int ky = 1; ky < 16; ++ky)
            sc += go[ky * 2] * cy[ky] - go[ky * 2 + 1] * sy[ky];
        sc *= (2.0f / 256.0f);
        const float* wo = pww + o * 32;      // uniform -> s_load
        float pw = pwb[o];
#pragma unroll
        for (int i = 0; i < 32; ++i) pw += hv[i] * wo[i];
        float u = sc + pw;
        h[hbase + ((size_t)o << 16) + x * 256 + y] = hv[o] + gelu_f(u);
    }
}

// ---------------------------------------------------------------------------
// Decoder with pre-transposed weights (s_load rows of 32) + fast GELU
// launch_bounds(256,4): VGPR cap 128 -> hf[32]+z1[32] register-resident
// ---------------------------------------------------------------------------
__global__ void __launch_bounds__(256, 4) k_decode(const float* __restrict__ h,
                         const float* __restrict__ w1t, const float* __restrict__ b1,
                         const float* __restrict__ w2t, const float* __restrict__ b2,
                         const float* __restrict__ w3, const float* __restrict__ b3,
                         float* __restrict__ out) {
    int g = blockIdx.x * 256 + threadIdx.x;
    int b = g >> 16, pos = g & 65535;
    float hf[32];
#pragma unroll
    for (int i = 0; i < 32; ++i) hf[i] = h[((size_t)(b * 32 + i) << 16) + pos];
    float res[3];
    for (int d = 0; d < 3; ++d) {
        float z1[32];
        const float* w1p = w1t + d * 1024;
#pragma unroll 4
        for (int o = 0; o < 32; ++o) {
            const float* wrow = w1p + o * 32;    // uniform -> s_load
            float a = b1[d * 32 + o];
#pragma unroll
            for (int i = 0; i < 32; ++i) a += hf[i] * wrow[i];
            z1[o] = gelu_f(a);
        }
        float z3 = b3[d];
        const float* w2p = w2t + d * 4096;
#pragma unroll 2
        for (int j = 0; j < 128; ++j) {
            const float* wrow = w2p + j * 32;    // uniform -> s_load
            float a = b2[d * 128 + j];
#pragma unroll
            for (int i = 0; i < 32; ++i) a += z1[i] * wrow[i];
            z3 += gelu_f(a) * w3[d * 128 + j];
        }
        res[d] = z3;
    }
    out[(size_t)g * 3 + 0] = res[0];
    out[(size_t)g * 3 + 1] = res[1];
    out[(size_t)g * 3 + 2] = res[2];
}

// ---------------------------------------------------------------------------
// Workspace (floats): gy and gi share one region (disjoint lifetimes).
// Total = 19,028,992 floats = 76.1 MB (proven safe in rounds 3-4).
// ---------------------------------------------------------------------------
extern "C" void kernel_launch(void* const* d_in, const int* in_sizes, int n_in,
                              void* d_out, int out_size, void* d_ws, size_t ws_size,
                              hipStream_t stream) {
    const float* bc      = (const float*)d_in[0];
    const float* xg      = (const float*)d_in[1];
    const float* yg      = (const float*)d_in[2];
    const float* mlp1_w  = (const float*)d_in[3];
    const float* mlp1_b  = (const float*)d_in[4];
    const float* spec_wr = (const float*)d_in[5];
    const float* spec_wi = (const float*)d_in[6];
    const float* pw_w    = (const float*)d_in[7];
    const float* pw_b    = (const float*)d_in[8];
    const float* dec_w1  = (const float*)d_in[9];
    const float* dec_b1  = (const float*)d_in[10];
    const float* dec_w2  = (const float*)d_in[11];
    const float* dec_b2  = (const float*)d_in[12];
    const float* dec_w3  = (const float*)d_in[13];
    const float* dec_b3  = (const float*)d_in[14];
    float* out = (float*)d_out;

    float* h    = (float*)d_ws;               // 16,777,216 floats
    float* spec = h + 16777216;               //  2,097,152 (shared gy / gi)
    float* Xf   = spec + 2097152;             //    131,072
    float* Wf   = Xf + 131072;                //      8,192
    float* w1t  = Wf + 8192;                  //      3,072
    float* w2t  = w1t + 3072;                 //     12,288
    float* gy   = spec;
    float* gi   = spec;
    (void)ws_size; (void)n_in; (void)in_sizes; (void)out_size;

    k_twiddle<<<32, 256, 0, stream>>>(Wf);
    k_prep_dec<<<1, 256, 0, stream>>>(dec_w1, dec_w2, w1t, w2t);
    k_lift<<<2048, 256, 0, stream>>>(bc, xg, yg, mlp1_w, mlp1_b, h);
    for (int l = 0; l < NL; ++l) {
        k_fwd_y<<<1024, 256, 0, stream>>>(h, Wf, gy);
        k_fwd_x<<<256, 1024, 0, stream>>>(gy, Xf);
        k_spec<<<256, 1024, 0, stream>>>(Xf, spec_wr + (size_t)l * 262144,
                                         spec_wi + (size_t)l * 262144, gi);
        k_update<<<2048, 256, 0, stream>>>(h, gi, pw_w + l * 1024, pw_b + l * 32);
    }
    k_decode<<<2048, 256, 0, stream>>>(h, w1t, dec_b1, w2t, dec_b2,
                                       dec_w3, dec_b3, out);
}